// Round 6
// baseline (867.768 us; speedup 1.0000x reference)
//
#include <hip/hip_runtime.h>

typedef unsigned short u16;
typedef __attribute__((ext_vector_type(8))) short short8;
typedef __attribute__((ext_vector_type(4))) float f32x4;
typedef __attribute__((ext_vector_type(8))) unsigned short ushort8;
typedef __attribute__((ext_vector_type(4))) unsigned short ushort4v;

__device__ __forceinline__ u16 f2bf(float f) {
    unsigned int u = __float_as_uint(f);
    u += 0x7FFFu + ((u >> 16) & 1u);   // round-to-nearest-even
    return (u16)(u >> 16);
}
__device__ __forceinline__ float bf2f(u16 h) {
    return __uint_as_float(((unsigned int)h) << 16);
}

// ---------------------------------------------------------------------------
// One GEMM template, three modes, all C = alpha * A[M,K] * B[N,K]^T, bf16 in.
// Tile 128x128, BK=64, 4 waves, 4x4 MFMA 16x16x32 per wave.
//
// REG-STAGED pipeline (no global_load_lds anywhere).  Rationale: LDS-DMA ops
// are stores to LDS, so the compiler must drain vmcnt(0) at EVERY barrier
// while any are pending — which voided all 5 previous prefetch schemes
// (r0-r5 all ~103-115 us, staging capped at ~12 B/cy/CU = inflight/wall).
// Loads into REGISTERS carry no barrier-visibility requirement: they stay in
// flight across __syncthreads and are waited (counted, per-register) only at
// the ds_write that consumes them — after the whole compute phase.
//
//   prologue: LOADR(0); DSWR; sync;
//   loop t:   LOADR(t+1);            // 8 global_load_dwordx4 -> VGPRs, fly
//             COMPUTE(t);            // ds_read_b128 + 32 MFMA from LDS
//             sync;                  // readers of tile t done
//             DSWR;                  // regs -> LDS (vmcnt counted here)
//             sync;                  // tile t+1 visible
//
// LDS XOR swizzle (write-side controlled, read-side inverse):
//   16B granule (row, g) stored at column granule g ^ (row & 7).
//   Reads: 16-lane groups span 8 bank-quads 2-way => conflict-free.
//   Writes: 2 rows x 8 granules per 16-lane group, 2-way => conflict-free.
// Global reads are NATURAL layout: each wave reads 8 rows x 128 B contiguous.
//
// MODE 0: fused QKV projection. A=xbf[16384,768], B=wt[2304,768] (3 W^T stacked)
//         grid 2304: f&7=xcd owns x row-tiles [16*xcd,16*xcd+16); c=u>>4 picks
//         W col-tile 0..17 -> which = c/6 routes to Q / K / V^T outputs.
// MODE 1: logits S_b = 0.125 * Q_b K_b^T. grid 2048: f&7 = batch = xcd,
//         panels of 4 row-tiles so live set (Q panel + K_b) < 4MB L2.
// MODE 2: out_b = A_b V_b (A=softmaxed S bf16, B=V^T), fp32 out. grid 768:
//         f&7 = batch, panels of 2 row-tiles.
// ---------------------------------------------------------------------------
template <int MODE>
__global__ __launch_bounds__(256, 3) void gemm_bt(
    const u16* __restrict__ A, const u16* __restrict__ B,
    void* __restrict__ O0, void* __restrict__ O1, void* __restrict__ O2,
    float alpha)
{
    constexpr int K   = (MODE == 2) ? 2048 : 768;
    constexpr int lda = (MODE == 2) ? 2048 : 768;
    constexpr int ldb = (MODE == 2) ? 2048 : 768;

    __shared__ __align__(16) u16 As[128 * 64];   // 16 KiB
    __shared__ __align__(16) u16 Bs[128 * 64];   // 16 KiB

    const int f = blockIdx.x;
    const int xcd = f & 7;
    const int u = f >> 3;

    int tm, bn, cn, which = 0;
    long aoff = 0, boff = 0;
    if constexpr (MODE == 0) {
        const int c = u >> 4;            // 0..17
        const int rl = u & 15;
        tm = (xcd * 16 + rl) * 128;
        bn = c * 128;
        which = c / 6;
        cn = (c % 6) * 128;
    } else if constexpr (MODE == 1) {
        const int p = u >> 6, t = u & 63, c = t >> 2, rl = t & 3;
        tm = (p * 4 + rl) * 128;
        bn = cn = c * 128;
        aoff = (long)xcd * 2048 * 768;
        boff = aoff;
    } else {
        const int p = u / 12, t = u % 12, c = t >> 1, rl = t & 1;
        tm = (p * 2 + rl) * 128;
        bn = cn = c * 128;
        aoff = (long)xcd * 2048 * 2048;
        boff = (long)xcd * 768 * 2048;
    }

    const u16* Ab = A + aoff;
    const u16* Bb = B + boff;

    const int tid  = threadIdx.x;
    const int lane = tid & 63;
    const int wave = tid >> 6;
    const int wr = wave >> 1;
    const int wc = wave & 1;

    f32x4 acc[4][4] = {};

    // --- staging addressing: thread handles rows srow+{0,32,64,96}, granule sg ---
    const int srow = tid >> 3;                 // 0..31
    const int sg   = tid & 7;                  // natural 16B-granule in K
    const int dcol = (sg ^ (srow & 7)) * 8;    // swizzled LDS column (elems);
                                               // (srow+32k)&7 == srow&7 -> same for all 4 parts
    const u16* Agp = Ab + (long)(tm + srow) * lda + sg * 8;
    const u16* Bgp = Bb + (long)(bn + srow) * ldb + sg * 8;
    u16* Adst = As + srow * 64 + dcol;
    u16* Bdst = Bs + srow * 64 + dcol;

    uint4 ra[4], rb[4];

#define LOADR(K0) do { _Pragma("unroll") \
    for (int p = 0; p < 4; ++p) { \
        ra[p] = *(const uint4*)(Agp + (K0) + (long)p * 32 * lda); \
        rb[p] = *(const uint4*)(Bgp + (K0) + (long)p * 32 * ldb); } \
} while (0)

#define DSWR() do { _Pragma("unroll") \
    for (int p = 0; p < 4; ++p) { \
        *(uint4*)(Adst + p * 32 * 64) = ra[p]; \
        *(uint4*)(Bdst + p * 32 * 64) = rb[p]; } \
} while (0)

    // --- fragment read bases (swizzle-inverse).  rows = lane&15 so row&7 = lane&7 ---
    const int rrow = lane & 15;
    const int lx   = lane & 7;
    const int g0 = ((lane >> 4)    ) ^ lx;     // K-half 0 granule
    const int g1 = ((lane >> 4) | 4) ^ lx;     // K-half 1 granule
    const u16* a0 = As + (wr * 64 + rrow) * 64 + g0 * 8;
    const u16* a1 = As + (wr * 64 + rrow) * 64 + g1 * 8;
    const u16* b0 = Bs + (wc * 64 + rrow) * 64 + g0 * 8;
    const u16* b1 = Bs + (wc * 64 + rrow) * 64 + g1 * 8;

#define HALF(AP, BP) do { \
    short8 a[4], b[4]; \
    _Pragma("unroll") \
    for (int i = 0; i < 4; ++i) a[i] = *(const short8*)((AP) + i * 16 * 64); \
    _Pragma("unroll") \
    for (int j = 0; j < 4; ++j) b[j] = *(const short8*)((BP) + j * 16 * 64); \
    _Pragma("unroll") \
    for (int i = 0; i < 4; ++i) \
    _Pragma("unroll") \
        for (int j = 0; j < 4; ++j) \
            acc[i][j] = __builtin_amdgcn_mfma_f32_16x16x32_bf16( \
                a[i], b[j], acc[i][j], 0, 0, 0); \
} while (0)

    // prologue: tile 0 through regs into LDS
    LOADR(0);
    DSWR();
    __syncthreads();

#pragma unroll 1
    for (int k0 = 0; k0 < K; k0 += 64) {
        const bool more = (k0 + 64 < K);
        if (more) LOADR(k0 + 64);   // flies across the whole compute phase
        HALF(a0, b0);
        HALF(a1, b1);
        __syncthreads();            // tile-k0 readers done
        if (more) {
            DSWR();                 // counted vmcnt waits happen here
            __syncthreads();        // tile k0+64 visible
        }
    }

#undef HALF
#undef DSWR
#undef LOADR

    // Epilogue. C/D layout: col = lane&15, row = (lane>>4)*4 + r
#pragma unroll
    for (int i = 0; i < 4; ++i) {
        const int row0 = tm + wr * 64 + i * 16 + ((lane >> 4) << 2);
#pragma unroll
        for (int j = 0; j < 4; ++j) {
            const int col = cn + wc * 64 + j * 16 + (lane & 15);
#pragma unroll
            for (int r = 0; r < 4; ++r) {
                const int row = row0 + r;
                const float val = acc[i][j][r] * alpha;
                if constexpr (MODE == 0) {
                    if (which == 0)
                        ((u16*)O0)[(long)row * 768 + col] = f2bf(val);
                    else if (which == 1)
                        ((u16*)O1)[(long)row * 768 + col] = f2bf(val);
                    else  // V^T: [b, col, s]
                        ((u16*)O2)[((long)(row >> 11) * 768 + col) * 2048 + (row & 2047)] = f2bf(val);
                } else if constexpr (MODE == 1) {
                    ((u16*)O0)[(long)xcd * 2048 * 2048 + (long)row * 2048 + col] = f2bf(val);
                } else {
                    ((float*)O0)[(long)xcd * 2048 * 768 + (long)row * 768 + col] = val;
                }
            }
        }
    }
}

// ---------------------------------------------------------------------------
__global__ __launch_bounds__(256) void cvt_x_kernel(
    const float4* __restrict__ x, ushort4v* __restrict__ out, int n4)
{
    int i = blockIdx.x * 256 + threadIdx.x;
    if (i < n4) {
        float4 f = x[i];
        ushort4v o;
        o.x = f2bf(f.x); o.y = f2bf(f.y); o.z = f2bf(f.z); o.w = f2bf(f.w);
        out[i] = o;
    }
}

// w[3][768][768] (m,d,o)  ->  wt[3][768][768] (m,o,d), bf16
__global__ __launch_bounds__(256) void cvt_w_kernel(
    const float* __restrict__ w, u16* __restrict__ wt)
{
    int i = blockIdx.x * 256 + threadIdx.x;   // total 3*768*768
    int d = i % 768;
    int o = (i / 768) % 768;
    int m = i / (768 * 768);
    wt[i] = f2bf(w[((long)m * 768 + d) * 768 + o]);
}

// one block per row, 2048 bf16 logits in-place -> softmax probs (bf16)
__global__ __launch_bounds__(256) void softmax_kernel(u16* __restrict__ S)
{
    const long row = blockIdx.x;
    u16* p = S + row * 2048;
    const int t = threadIdx.x;
    const int lane = t & 63;
    const int wave = t >> 6;
    __shared__ float red[8];

    ushort8 raw = *(const ushort8*)(p + t * 8);
    float v[8];
    float m = -1e30f;
#pragma unroll
    for (int i = 0; i < 8; ++i) { v[i] = bf2f(raw[i]); m = fmaxf(m, v[i]); }
#pragma unroll
    for (int off = 1; off < 64; off <<= 1) m = fmaxf(m, __shfl_xor(m, off, 64));
    if (lane == 0) red[wave] = m;
    __syncthreads();
    m = fmaxf(fmaxf(red[0], red[1]), fmaxf(red[2], red[3]));

    float s = 0.f;
#pragma unroll
    for (int i = 0; i < 8; ++i) { v[i] = __expf(v[i] - m); s += v[i]; }
#pragma unroll
    for (int off = 1; off < 64; off <<= 1) s += __shfl_xor(s, off, 64);
    if (lane == 0) red[4 + wave] = s;
    __syncthreads();
    s = (red[4] + red[5]) + (red[6] + red[7]);

    const float inv = 1.0f / s;
    ushort8 out;
#pragma unroll
    for (int i = 0; i < 8; ++i) out[i] = f2bf(v[i] * inv);
    *(ushort8*)(p + t * 8) = out;
}

// ---------------------------------------------------------------------------
extern "C" void kernel_launch(void* const* d_in, const int* in_sizes, int n_in,
                              void* d_out, int out_size, void* d_ws, size_t ws_size,
                              hipStream_t stream)
{
    const float* x  = (const float*)d_in[0];   // [8,2048,768]
    const float* wk = (const float*)d_in[1];   // [3,768,768]
    float* out = (float*)d_out;                // [8,2048,768]

    char* ws = (char*)d_ws;
    u16* xbf = (u16*)(ws);                       // 16384x768        25.2 MB
    u16* wt  = (u16*)(ws + 25165824);            // 3x768x768 (W^T)   3.5 MB
    u16* qbf = (u16*)(ws + 28704768);            // 16384x768        25.2 MB
    u16* kbf = (u16*)(ws + 53870592);            // 16384x768        25.2 MB
    u16* vt  = (u16*)(ws + 79036416);            // 8x768x2048       25.2 MB
    u16* S   = (u16*)(ws + 104202240);           // 8x2048x2048      67.1 MB

    // 1. conversions
    cvt_x_kernel<<<dim3(12288), dim3(256), 0, stream>>>(
        (const float4*)x, (ushort4v*)xbf, 3145728);
    cvt_w_kernel<<<dim3(6912), dim3(256), 0, stream>>>(wk, wt);

    // 2. fused QKV projections (one dispatch, 18 col-tiles share x row-tiles)
    gemm_bt<0><<<dim3(2304), dim3(256), 0, stream>>>(
        xbf, wt, qbf, kbf, vt, 1.0f);

    // 3. logits: S_b = 0.125 * Q_b K_b^T   (batch <-> XCD)
    gemm_bt<1><<<dim3(2048), dim3(256), 0, stream>>>(
        qbf, kbf, S, nullptr, nullptr, 0.125f);

    // 4. softmax rows (in place, bf16)
    softmax_kernel<<<dim3(16384), dim3(256), 0, stream>>>(S);

    // 5. out_b = A_b V_b
    gemm_bt<2><<<dim3(768), dim3(256), 0, stream>>>(
        S, vt, out, nullptr, nullptr, 1.0f);
}

// Round 7
// 833.616 us; speedup vs baseline: 1.0410x; 1.0410x over previous
//
#include <hip/hip_runtime.h>

typedef unsigned short u16;
typedef __attribute__((ext_vector_type(8))) short short8;
typedef __attribute__((ext_vector_type(4))) float f32x4;
typedef __attribute__((ext_vector_type(8))) unsigned short ushort8;
typedef __attribute__((ext_vector_type(4))) unsigned short ushort4v;

__device__ __forceinline__ u16 f2bf(float f) {
    unsigned int u = __float_as_uint(f);
    u += 0x7FFFu + ((u >> 16) & 1u);   // round-to-nearest-even
    return (u16)(u >> 16);
}
__device__ __forceinline__ float bf2f(u16 h) {
    return __uint_as_float(((unsigned int)h) << 16);
}

// ---------------------------------------------------------------------------
// One GEMM template, three modes, all C = alpha * A[M,K] * B[N,K]^T, bf16 in.
// Tile 128x128, BK=64, 4 waves, 4x4 MFMA 16x16x32 per wave.
//
// REG-STAGED pipeline (no global_load_lds anywhere).  LDS-DMA ops are stores
// to LDS, so the compiler must drain vmcnt(0) at EVERY barrier while any are
// pending — which voided all global_load_lds prefetch schemes (r0-r5, all
// ~103-115 us).  Loads into REGISTERS carry no barrier-visibility
// requirement: they stay in flight across __syncthreads and are waited
// (counted, per-register) only at the ds_write that consumes them — after
// the whole compute phase.
//
//   prologue: LOADR(0); DSWR; sync;
//   loop t:   LOADR(t+1);            // 8 global_load_dwordx4 -> VGPRs, fly
//             COMPUTE(t);            // ds_read_b128 + 32 MFMA from LDS
//             sync;                  // readers of tile t done
//             DSWR;                  // regs -> LDS (vmcnt counted here)
//             sync;                  // tile t+1 visible
//
// REGISTER BUDGET (r6 lesson): acc 64 (AGPR) + stage 32 + frags 16 +
// addressing ~30 ~= 145 total on the unified file -> 3 waves/SIMD naturally.
// Do NOT force a min-occupancy launch bound: (256,3) squeezed the budget to
// the 128 class and spilled ra/rb in the K-loop (909 MB scratch writes per
// dispatch, 3x regression).  Plain (256) leaves the cap at 256 -> no spill.
//
// LDS XOR swizzle (write-side controlled, read-side inverse):
//   16B granule (row, g) stored at column granule g ^ (row & 7).
//   Reads: 16-lane groups 2-way per bank-quad => free.  Writes: each
//   16-lane phase covers all 32 banks 2-way => free.
// Global reads are NATURAL layout: each wave reads 8 rows x 128 B contiguous.
//
// MODE 0: fused QKV projection. A=xbf[16384,768], B=wt[2304,768] (3 W^T stacked)
//         grid 2304: f&7=xcd owns x row-tiles [16*xcd,16*xcd+16); c=u>>4 picks
//         W col-tile 0..17 -> which = c/6 routes to Q / K / V^T outputs.
// MODE 1: logits S_b = 0.125 * Q_b K_b^T. grid 2048: f&7 = batch = xcd,
//         panels of 4 row-tiles so live set (Q panel + K_b) < 4MB L2.
// MODE 2: out_b = A_b V_b (A=softmaxed S bf16, B=V^T), fp32 out. grid 768:
//         f&7 = batch, panels of 2 row-tiles.
// ---------------------------------------------------------------------------
template <int MODE>
__global__ __launch_bounds__(256) void gemm_bt(
    const u16* __restrict__ A, const u16* __restrict__ B,
    void* __restrict__ O0, void* __restrict__ O1, void* __restrict__ O2,
    float alpha)
{
    constexpr int K   = (MODE == 2) ? 2048 : 768;
    constexpr int lda = (MODE == 2) ? 2048 : 768;
    constexpr int ldb = (MODE == 2) ? 2048 : 768;

    __shared__ __align__(16) u16 As[128 * 64];   // 16 KiB
    __shared__ __align__(16) u16 Bs[128 * 64];   // 16 KiB

    const int f = blockIdx.x;
    const int xcd = f & 7;
    const int u = f >> 3;

    int tm, bn, cn, which = 0;
    long aoff = 0, boff = 0;
    if constexpr (MODE == 0) {
        const int c = u >> 4;            // 0..17
        const int rl = u & 15;
        tm = (xcd * 16 + rl) * 128;
        bn = c * 128;
        which = c / 6;
        cn = (c % 6) * 128;
    } else if constexpr (MODE == 1) {
        const int p = u >> 6, t = u & 63, c = t >> 2, rl = t & 3;
        tm = (p * 4 + rl) * 128;
        bn = cn = c * 128;
        aoff = (long)xcd * 2048 * 768;
        boff = aoff;
    } else {
        const int p = u / 12, t = u % 12, c = t >> 1, rl = t & 1;
        tm = (p * 2 + rl) * 128;
        bn = cn = c * 128;
        aoff = (long)xcd * 2048 * 2048;
        boff = (long)xcd * 768 * 2048;
    }

    const u16* Ab = A + aoff;
    const u16* Bb = B + boff;

    const int tid  = threadIdx.x;
    const int lane = tid & 63;
    const int wave = tid >> 6;
    const int wr = wave >> 1;
    const int wc = wave & 1;

    f32x4 acc[4][4] = {};

    // --- staging addressing: thread handles rows srow+{0,32,64,96}, granule sg ---
    const int srow = tid >> 3;                 // 0..31
    const int sg   = tid & 7;                  // natural 16B-granule in K
    const int dcol = (sg ^ (srow & 7)) * 8;    // swizzled LDS column (elems);
                                               // (srow+32k)&7 == srow&7 -> same for all 4 parts
    const u16* Agp = Ab + (long)(tm + srow) * lda + sg * 8;
    const u16* Bgp = Bb + (long)(bn + srow) * ldb + sg * 8;
    u16* Adst = As + srow * 64 + dcol;
    u16* Bdst = Bs + srow * 64 + dcol;

    uint4 ra[4], rb[4];

#define LOADR(K0) do { _Pragma("unroll") \
    for (int p = 0; p < 4; ++p) { \
        ra[p] = *(const uint4*)(Agp + (K0) + (long)p * 32 * lda); \
        rb[p] = *(const uint4*)(Bgp + (K0) + (long)p * 32 * ldb); } \
} while (0)

#define DSWR() do { _Pragma("unroll") \
    for (int p = 0; p < 4; ++p) { \
        *(uint4*)(Adst + p * 32 * 64) = ra[p]; \
        *(uint4*)(Bdst + p * 32 * 64) = rb[p]; } \
} while (0)

    // --- fragment read bases (swizzle-inverse).  rows = lane&15 so row&7 = lane&7 ---
    const int rrow = lane & 15;
    const int lx   = lane & 7;
    const int g0 = ((lane >> 4)    ) ^ lx;     // K-half 0 granule
    const int g1 = ((lane >> 4) | 4) ^ lx;     // K-half 1 granule
    const u16* a0 = As + (wr * 64 + rrow) * 64 + g0 * 8;
    const u16* a1 = As + (wr * 64 + rrow) * 64 + g1 * 8;
    const u16* b0 = Bs + (wc * 64 + rrow) * 64 + g0 * 8;
    const u16* b1 = Bs + (wc * 64 + rrow) * 64 + g1 * 8;

#define HALF(AP, BP) do { \
    short8 a[4], b[4]; \
    _Pragma("unroll") \
    for (int i = 0; i < 4; ++i) a[i] = *(const short8*)((AP) + i * 16 * 64); \
    _Pragma("unroll") \
    for (int j = 0; j < 4; ++j) b[j] = *(const short8*)((BP) + j * 16 * 64); \
    _Pragma("unroll") \
    for (int i = 0; i < 4; ++i) \
    _Pragma("unroll") \
        for (int j = 0; j < 4; ++j) \
            acc[i][j] = __builtin_amdgcn_mfma_f32_16x16x32_bf16( \
                a[i], b[j], acc[i][j], 0, 0, 0); \
} while (0)

    // prologue: tile 0 through regs into LDS
    LOADR(0);
    DSWR();
    __syncthreads();

#pragma unroll 1
    for (int k0 = 0; k0 < K; k0 += 64) {
        const bool more = (k0 + 64 < K);
        if (more) LOADR(k0 + 64);   // flies across the whole compute phase
        HALF(a0, b0);
        HALF(a1, b1);
        __syncthreads();            // tile-k0 readers done
        if (more) {
            DSWR();                 // counted vmcnt waits happen here
            __syncthreads();        // tile k0+64 visible
        }
    }

#undef HALF
#undef DSWR
#undef LOADR

    // Epilogue. C/D layout: col = lane&15, row = (lane>>4)*4 + r
#pragma unroll
    for (int i = 0; i < 4; ++i) {
        const int row0 = tm + wr * 64 + i * 16 + ((lane >> 4) << 2);
#pragma unroll
        for (int j = 0; j < 4; ++j) {
            const int col = cn + wc * 64 + j * 16 + (lane & 15);
#pragma unroll
            for (int r = 0; r < 4; ++r) {
                const int row = row0 + r;
                const float val = acc[i][j][r] * alpha;
                if constexpr (MODE == 0) {
                    if (which == 0)
                        ((u16*)O0)[(long)row * 768 + col] = f2bf(val);
                    else if (which == 1)
                        ((u16*)O1)[(long)row * 768 + col] = f2bf(val);
                    else  // V^T: [b, col, s]
                        ((u16*)O2)[((long)(row >> 11) * 768 + col) * 2048 + (row & 2047)] = f2bf(val);
                } else if constexpr (MODE == 1) {
                    ((u16*)O0)[(long)xcd * 2048 * 2048 + (long)row * 2048 + col] = f2bf(val);
                } else {
                    ((float*)O0)[(long)xcd * 2048 * 768 + (long)row * 768 + col] = val;
                }
            }
        }
    }
}

// ---------------------------------------------------------------------------
__global__ __launch_bounds__(256) void cvt_x_kernel(
    const float4* __restrict__ x, ushort4v* __restrict__ out, int n4)
{
    int i = blockIdx.x * 256 + threadIdx.x;
    if (i < n4) {
        float4 f = x[i];
        ushort4v o;
        o.x = f2bf(f.x); o.y = f2bf(f.y); o.z = f2bf(f.z); o.w = f2bf(f.w);
        out[i] = o;
    }
}

// w[3][768][768] (m,d,o)  ->  wt[3][768][768] (m,o,d), bf16
__global__ __launch_bounds__(256) void cvt_w_kernel(
    const float* __restrict__ w, u16* __restrict__ wt)
{
    int i = blockIdx.x * 256 + threadIdx.x;   // total 3*768*768
    int d = i % 768;
    int o = (i / 768) % 768;
    int m = i / (768 * 768);
    wt[i] = f2bf(w[((long)m * 768 + d) * 768 + o]);
}

// one block per row, 2048 bf16 logits in-place -> softmax probs (bf16)
__global__ __launch_bounds__(256) void softmax_kernel(u16* __restrict__ S)
{
    const long row = blockIdx.x;
    u16* p = S + row * 2048;
    const int t = threadIdx.x;
    const int lane = t & 63;
    const int wave = t >> 6;
    __shared__ float red[8];

    ushort8 raw = *(const ushort8*)(p + t * 8);
    float v[8];
    float m = -1e30f;
#pragma unroll
    for (int i = 0; i < 8; ++i) { v[i] = bf2f(raw[i]); m = fmaxf(m, v[i]); }
#pragma unroll
    for (int off = 1; off < 64; off <<= 1) m = fmaxf(m, __shfl_xor(m, off, 64));
    if (lane == 0) red[wave] = m;
    __syncthreads();
    m = fmaxf(fmaxf(red[0], red[1]), fmaxf(red[2], red[3]));

    float s = 0.f;
#pragma unroll
    for (int i = 0; i < 8; ++i) { v[i] = __expf(v[i] - m); s += v[i]; }
#pragma unroll
    for (int off = 1; off < 64; off <<= 1) s += __shfl_xor(s, off, 64);
    if (lane == 0) red[4 + wave] = s;
    __syncthreads();
    s = (red[4] + red[5]) + (red[6] + red[7]);

    const float inv = 1.0f / s;
    ushort8 out;
#pragma unroll
    for (int i = 0; i < 8; ++i) out[i] = f2bf(v[i] * inv);
    *(ushort8*)(p + t * 8) = out;
}

// ---------------------------------------------------------------------------
extern "C" void kernel_launch(void* const* d_in, const int* in_sizes, int n_in,
                              void* d_out, int out_size, void* d_ws, size_t ws_size,
                              hipStream_t stream)
{
    const float* x  = (const float*)d_in[0];   // [8,2048,768]
    const float* wk = (const float*)d_in[1];   // [3,768,768]
    float* out = (float*)d_out;                // [8,2048,768]

    char* ws = (char*)d_ws;
    u16* xbf = (u16*)(ws);                       // 16384x768        25.2 MB
    u16* wt  = (u16*)(ws + 25165824);            // 3x768x768 (W^T)   3.5 MB
    u16* qbf = (u16*)(ws + 28704768);            // 16384x768        25.2 MB
    u16* kbf = (u16*)(ws + 53870592);            // 16384x768        25.2 MB
    u16* vt  = (u16*)(ws + 79036416);            // 8x768x2048       25.2 MB
    u16* S   = (u16*)(ws + 104202240);           // 8x2048x2048      67.1 MB

    // 1. conversions
    cvt_x_kernel<<<dim3(12288), dim3(256), 0, stream>>>(
        (const float4*)x, (ushort4v*)xbf, 3145728);
    cvt_w_kernel<<<dim3(6912), dim3(256), 0, stream>>>(wk, wt);

    // 2. fused QKV projections (one dispatch, 18 col-tiles share x row-tiles)
    gemm_bt<0><<<dim3(2304), dim3(256), 0, stream>>>(
        xbf, wt, qbf, kbf, vt, 1.0f);

    // 3. logits: S_b = 0.125 * Q_b K_b^T   (batch <-> XCD)
    gemm_bt<1><<<dim3(2048), dim3(256), 0, stream>>>(
        qbf, kbf, S, nullptr, nullptr, 0.125f);

    // 4. softmax rows (in place, bf16)
    softmax_kernel<<<dim3(16384), dim3(256), 0, stream>>>(S);

    // 5. out_b = A_b V_b
    gemm_bt<2><<<dim3(768), dim3(256), 0, stream>>>(
        S, vt, out, nullptr, nullptr, 1.0f);
}

// Round 9
// 373.304 us; speedup vs baseline: 2.3246x; 2.2331x over previous
//
#include <hip/hip_runtime.h>

typedef unsigned short u16;
typedef __attribute__((ext_vector_type(8))) short short8;
typedef __attribute__((ext_vector_type(4))) float f32x4;
typedef __attribute__((ext_vector_type(8))) unsigned short ushort8;
typedef __attribute__((ext_vector_type(4))) unsigned short ushort4v;

__device__ __forceinline__ u16 f2bf(float f) {
    unsigned int u = __float_as_uint(f);
    u += 0x7FFFu + ((u >> 16) & 1u);   // round-to-nearest-even
    return (u16)(u >> 16);
}
__device__ __forceinline__ float bf2f(u16 h) {
    return __uint_as_float(((unsigned int)h) << 16);
}

__device__ __forceinline__ void gld_lds16(const void* g, void* l) {
    __builtin_amdgcn_global_load_lds(
        (const __attribute__((address_space(1))) unsigned int*)g,
        (__attribute__((address_space(3))) unsigned int*)l,
        16, 0, 0);
}

// ---------------------------------------------------------------------------
// C = alpha * A[M,K] * B[N,K]^T, bf16 in.  Block tile 128x256, BK=32,
// 4 waves (2Mx2N), wave-tile 64x128 (acc 4x8 of 16x16x32 MFMA).
//
// WHY THIS SHAPE (r0-r7 postmortem): r0-r5 (64x64 wave-tiles) all sustain
// ~93 LDS-B/cy/CU — at the measured ds_read_b128 ceiling (m134: ~85, peak
// 128) — so every schedule variant was LDS-THROUGHPUT-bound and invariant
// (~103-115 us).  hipBLASLt runs the same ~90 B/cy but at 26.7 LDS-B/KFLOP
// (big wave tiles) vs our 45.8 -> 4x the FLOPs.  Traffic per FLOP scales as
// (Mw+Nw)/(Mw*Nw): 64x128 cuts it 25% and doubles FLOP per barrier while
// KEEPING r0's winning structure: 24 KB single-buffer LDS, gld_lds staging
// (zero stage VGPRs — reg-staging spilled in r6 AND r7), 2-sync loop,
// 2 blocks/CU co-residency to cross-fill latency.
//
// REGISTERS: acc 128 (unified-file AGPR) + ~90 arch ~= 220.
// __launch_bounds__(256, 2) -> cap 256/wave: the compiler CANNOT repeat
// r7's trick of targeting 3 waves/SIMD and spilling (WRITE_SIZE tripwire:
// must be ~74 MB total, not 500+).
//
// (r8 submitted this exact kernel; container failed twice — same infra
// signature as r3, which ran clean on identical resubmission in r4.
// Audit found no hang path: uniform barriers, verified index math,
// 220 < 256 reg budget.  Resubmitting unchanged.)
//
// LDS XOR swizzle (r0-verified, unchanged): chunk (row, kc) of 8 bf16 at
// 16B-granule g = row*4 + (kc ^ ((row>>1)&3)); write side realized by
// permuting per-lane GLOBAL addresses within each row's 64B line.
//
// MODE 0: fused QKV. A=xbf[16384,768], B=wt[2304,768] (3 W^T stacked).
//         grid 1152: f&7=xcd owns 16 row-tiles; c=u>>4 in 0..8; which=c/3.
// MODE 1: logits S_b = 0.125 * Q_b K_b^T. grid 1024: f&7 = batch = xcd,
//         within batch 4 panels x (8 col x 4 row) tiles.
// MODE 2: out_b = A_b V_b (A=softmaxed S bf16, B=V^T), fp32 out. grid 384:
//         f&7 = batch, per batch 8 panels x (3 col x 2 row).
// ---------------------------------------------------------------------------
template <int MODE>
__global__ __launch_bounds__(256, 2) void gemm_bt(
    const u16* __restrict__ A, const u16* __restrict__ B,
    void* __restrict__ O0, void* __restrict__ O1, void* __restrict__ O2,
    float alpha)
{
    constexpr int K   = (MODE == 2) ? 2048 : 768;
    constexpr int lda = (MODE == 2) ? 2048 : 768;
    constexpr int ldb = (MODE == 2) ? 2048 : 768;

    __shared__ u16 As[128 * 32];   //  8 KB
    __shared__ u16 Bs[256 * 32];   // 16 KB

    const int f = blockIdx.x;
    const int xcd = f & 7;
    const int u = f >> 3;

    int tm, bn, cn, which = 0;
    long aoff = 0, boff = 0;
    if constexpr (MODE == 0) {
        const int c = u >> 4;            // 0..8 (256-col tile of wt)
        const int rl = u & 15;
        tm = (xcd * 16 + rl) * 128;
        bn = c * 256;
        which = c / 3;
        cn = (c % 3) * 256;
    } else if constexpr (MODE == 1) {
        const int p = u >> 5, t = u & 31, c = t >> 2, rl = t & 3;
        tm = (p * 4 + rl) * 128;         // panel of 4 row-tiles
        bn = cn = c * 256;               // 8 col-tiles
        aoff = (long)xcd * 2048 * 768;
        boff = aoff;
    } else {
        const int p = u / 6, t = u % 6, c = t >> 1, rl = t & 1;
        tm = (p * 2 + rl) * 128;         // panel of 2 row-tiles
        bn = cn = c * 256;               // 3 col-tiles
        aoff = (long)xcd * 2048 * 2048;
        boff = (long)xcd * 768 * 2048;
    }

    const u16* Ab = A + aoff;
    const u16* Bb = B + boff;

    const int tid  = threadIdx.x;
    const int lane = tid & 63;
    const int wave = tid >> 6;
    const int wr = wave >> 1;      // 0..1 -> rows wr*64
    const int wc = wave & 1;       // 0..1 -> cols wc*128

    f32x4 acc[4][8] = {};

    // swizzled read bases (verified in r0; row parity = lane parity for all frags)
    const int swz = ((lane >> 4) ^ ((lane >> 1) & 3)) * 8;
    const u16* a_base = As + (wr * 64 + (lane & 15)) * 32 + swz;
    const u16* b_base = Bs + (wc * 128 + (lane & 15)) * 32 + swz;

    // --- staging slots.  A: 512 chunks (2/thread), B: 1024 chunks (4/thread).
    // slot s -> (row = s>>2, kc = (s&3) ^ ((row>>1)&3)); global addr permuted
    // within the row's 64B line, LDS dest lane-linear (gld_lds requirement).
    const int sA0 = tid, sA1 = tid + 256;
    const int ra0 = sA0 >> 2, ka0 = (sA0 & 3) ^ ((ra0 >> 1) & 3);
    const int ra1 = sA1 >> 2, ka1 = (sA1 & 3) ^ ((ra1 >> 1) & 3);
    const long arow0 = (long)(tm + ra0) * lda + ka0 * 8;
    const long arow1 = (long)(tm + ra1) * lda + ka1 * 8;
    // B: slot s = tid + 256q -> row = (tid>>2) + 64q; (row>>1)&3 is q-invariant
    const int rb = tid >> 2, kb = (tid & 3) ^ ((rb >> 1) & 3);
    long brow[4];
#pragma unroll
    for (int q = 0; q < 4; ++q)
        brow[q] = (long)(bn + rb + 64 * q) * ldb + kb * 8;

#define STAGE(K0) do { \
    gld_lds16(Ab + arow0 + (K0), (void*)(As + sA0 * 8)); \
    gld_lds16(Ab + arow1 + (K0), (void*)(As + sA1 * 8)); \
    _Pragma("unroll") \
    for (int q = 0; q < 4; ++q) \
        gld_lds16(Bb + brow[q] + (K0), (void*)(Bs + tid * 8 + q * 2048)); \
} while (0)

#define COMPUTE() do { \
    short8 a[4]; \
    _Pragma("unroll") \
    for (int i = 0; i < 4; ++i) a[i] = *(const short8*)(a_base + i * 16 * 32); \
    _Pragma("unroll") \
    for (int j = 0; j < 8; ++j) { \
        const short8 bj = *(const short8*)(b_base + j * 16 * 32); \
        _Pragma("unroll") \
        for (int i = 0; i < 4; ++i) \
            acc[i][j] = __builtin_amdgcn_mfma_f32_16x16x32_bf16( \
                a[i], bj, acc[i][j], 0, 0, 0); \
    } \
} while (0)

#pragma unroll 1
    for (int k0 = 0; k0 < K; k0 += 32) {
        __syncthreads();           // previous tile's readers done (WAR)
        STAGE(k0);
        __syncthreads();           // tile visible (drains staging)
        COMPUTE();
    }

#undef STAGE
#undef COMPUTE

    // Epilogue. C/D layout: col = lane&15, row = (lane>>4)*4 + r
#pragma unroll
    for (int i = 0; i < 4; ++i) {
        const int row0 = tm + wr * 64 + i * 16 + ((lane >> 4) << 2);
#pragma unroll
        for (int j = 0; j < 8; ++j) {
            const int col = cn + wc * 128 + j * 16 + (lane & 15);
#pragma unroll
            for (int r = 0; r < 4; ++r) {
                const int row = row0 + r;
                const float val = acc[i][j][r] * alpha;
                if constexpr (MODE == 0) {
                    if (which == 0)
                        ((u16*)O0)[(long)row * 768 + col] = f2bf(val);
                    else if (which == 1)
                        ((u16*)O1)[(long)row * 768 + col] = f2bf(val);
                    else  // V^T: [b, col, s]
                        ((u16*)O2)[((long)(row >> 11) * 768 + col) * 2048 + (row & 2047)] = f2bf(val);
                } else if constexpr (MODE == 1) {
                    ((u16*)O0)[(long)xcd * 2048 * 2048 + (long)row * 2048 + col] = f2bf(val);
                } else {
                    ((float*)O0)[(long)xcd * 2048 * 768 + (long)row * 768 + col] = val;
                }
            }
        }
    }
}

// ---------------------------------------------------------------------------
__global__ __launch_bounds__(256) void cvt_x_kernel(
    const float4* __restrict__ x, ushort4v* __restrict__ out, int n4)
{
    int i = blockIdx.x * 256 + threadIdx.x;
    if (i < n4) {
        float4 f = x[i];
        ushort4v o;
        o.x = f2bf(f.x); o.y = f2bf(f.y); o.z = f2bf(f.z); o.w = f2bf(f.w);
        out[i] = o;
    }
}

// w[3][768][768] (m,d,o)  ->  wt[3][768][768] (m,o,d), bf16
__global__ __launch_bounds__(256) void cvt_w_kernel(
    const float* __restrict__ w, u16* __restrict__ wt)
{
    int i = blockIdx.x * 256 + threadIdx.x;   // total 3*768*768
    int d = i % 768;
    int o = (i / 768) % 768;
    int m = i / (768 * 768);
    wt[i] = f2bf(w[((long)m * 768 + d) * 768 + o]);
}

// one block per row, 2048 bf16 logits in-place -> softmax probs (bf16)
__global__ __launch_bounds__(256) void softmax_kernel(u16* __restrict__ S)
{
    const long row = blockIdx.x;
    u16* p = S + row * 2048;
    const int t = threadIdx.x;
    const int lane = t & 63;
    const int wave = t >> 6;
    __shared__ float red[8];

    ushort8 raw = *(const ushort8*)(p + t * 8);
    float v[8];
    float m = -1e30f;
#pragma unroll
    for (int i = 0; i < 8; ++i) { v[i] = bf2f(raw[i]); m = fmaxf(m, v[i]); }
#pragma unroll
    for (int off = 1; off < 64; off <<= 1) m = fmaxf(m, __shfl_xor(m, off, 64));
    if (lane == 0) red[wave] = m;
    __syncthreads();
    m = fmaxf(fmaxf(red[0], red[1]), fmaxf(red[2], red[3]));

    float s = 0.f;
#pragma unroll
    for (int i = 0; i < 8; ++i) { v[i] = __expf(v[i] - m); s += v[i]; }
#pragma unroll
    for (int off = 1; off < 64; off <<= 1) s += __shfl_xor(s, off, 64);
    if (lane == 0) red[4 + wave] = s;
    __syncthreads();
    s = (red[4] + red[5]) + (red[6] + red[7]);

    const float inv = 1.0f / s;
    ushort8 out;
#pragma unroll
    for (int i = 0; i < 8; ++i) out[i] = f2bf(v[i] * inv);
    *(ushort8*)(p + t * 8) = out;
}

// ---------------------------------------------------------------------------
extern "C" void kernel_launch(void* const* d_in, const int* in_sizes, int n_in,
                              void* d_out, int out_size, void* d_ws, size_t ws_size,
                              hipStream_t stream)
{
    const float* x  = (const float*)d_in[0];   // [8,2048,768]
    const float* wk = (const float*)d_in[1];   // [3,768,768]
    float* out = (float*)d_out;                // [8,2048,768]

    char* ws = (char*)d_ws;
    u16* xbf = (u16*)(ws);                       // 16384x768        25.2 MB
    u16* wt  = (u16*)(ws + 25165824);            // 3x768x768 (W^T)   3.5 MB
    u16* qbf = (u16*)(ws + 28704768);            // 16384x768        25.2 MB
    u16* kbf = (u16*)(ws + 53870592);            // 16384x768        25.2 MB
    u16* vt  = (u16*)(ws + 79036416);            // 8x768x2048       25.2 MB
    u16* S   = (u16*)(ws + 104202240);           // 8x2048x2048      67.1 MB

    // 1. conversions
    cvt_x_kernel<<<dim3(12288), dim3(256), 0, stream>>>(
        (const float4*)x, (ushort4v*)xbf, 3145728);
    cvt_w_kernel<<<dim3(6912), dim3(256), 0, stream>>>(wk, wt);

    // 2. fused QKV projections (9 col-tiles of 256 share x row-tiles)
    gemm_bt<0><<<dim3(1152), dim3(256), 0, stream>>>(
        xbf, wt, qbf, kbf, vt, 1.0f);

    // 3. logits: S_b = 0.125 * Q_b K_b^T   (batch <-> XCD)
    gemm_bt<1><<<dim3(1024), dim3(256), 0, stream>>>(
        qbf, kbf, S, nullptr, nullptr, 0.125f);

    // 4. softmax rows (in place, bf16)
    softmax_kernel<<<dim3(16384), dim3(256), 0, stream>>>(S);

    // 5. out_b = A_b V_b
    gemm_bt<2><<<dim3(384), dim3(256), 0, stream>>>(
        S, vt, out, nullptr, nullptr, 1.0f);
}

// Round 10
// 334.666 us; speedup vs baseline: 2.5929x; 1.1155x over previous
//
#include <hip/hip_runtime.h>

typedef unsigned short u16;
typedef __attribute__((ext_vector_type(8))) short short8;
typedef __attribute__((ext_vector_type(4))) float f32x4;
typedef __attribute__((ext_vector_type(8))) unsigned short ushort8;
typedef __attribute__((ext_vector_type(4))) unsigned short ushort4v;

__device__ __forceinline__ u16 f2bf(float f) {
    unsigned int u = __float_as_uint(f);
    u += 0x7FFFu + ((u >> 16) & 1u);   // round-to-nearest-even
    return (u16)(u >> 16);
}
__device__ __forceinline__ float bf2f(u16 h) {
    return __uint_as_float(((unsigned int)h) << 16);
}

__device__ __forceinline__ void gld_lds16(const void* g, void* l) {
    __builtin_amdgcn_global_load_lds(
        (const __attribute__((address_space(1))) unsigned int*)g,
        (__attribute__((address_space(3))) unsigned int*)l,
        16, 0, 0);
}

// ---------------------------------------------------------------------------
// C = alpha * A[M,K] * B[N,K]^T, bf16 in.  Tile 128x128, BK=64, 4 waves,
// 64x64 wave-tile (4x4 MFMA 16x16x32, two K-halves per stage).
//
// DRAIN-COUNT MODEL (fits r0-r9): per K-step wall ~= one exposed
// memory-latency drain (~900 cy, the vmcnt(0) the compiler inserts at the
// post-STAGE barrier) + resident MFMA work (~235 cy at 3 blk/CU).  r0 paid
// 24 drains per 768-K block; r9 cut LDS traffic but kept 24 drains and lost
// occupancy -> slower.  THIS kernel halves drains (12 per 768-K): BK=64,
// one stage+sync per 64-K, 32 MFMA/wave per drain.  Everything else is
// r0's verified structure: gld_lds staging (zero stage VGPRs — reg staging
// spilled in r6/r7), 2-sync single-buffer loop, plain __launch_bounds__(256)
// (forcing min-occupancy caused the r6/r7 spills), 3 blocks/CU co-residency.
// LDS 2x16 KB.  Tripwire: WRITE_SIZE must stay ~74 MB (no scratch).
//
// LDS swizzle (8 granules/row): 16B granule of global column-granule g in
// row r lives at slot g ^ (r&7).  Reads: per fragment, 8 lanes per
// bank-quad uniformly = the 8-cy wave minimum -> conflict-free (same
// balance property as r0's measured-zero map).  Staging: slot s = tid+256k
// -> row sr+32k, slot gs=tid&7, global granule g = gs ^ (sr&7) ((sr+32k)&7
// is k-invariant); each row's 8 granules permute inside its 128 B line ->
// full coalescing; LDS dest stays lane-linear as gld_lds requires.
//
// MODE 0: fused QKV. A=xbf[16384,768], B=wt[2304,768] (3 W^T stacked).
//         grid 2304: f&7=xcd owns row-tiles; c=u>>4 in 0..17; which=c/6.
// MODE 1: logits S_b = 0.125 * Q_b K_b^T. grid 2048: f&7 = batch = xcd,
//         panels of 4 row-tiles (live set Q panel + K_b < 4MB L2).
// MODE 2: out_b = A_b V_b (A=softmaxed S bf16, B=V^T), fp32 out. grid 768.
// ---------------------------------------------------------------------------
template <int MODE>
__global__ __launch_bounds__(256) void gemm_bt(
    const u16* __restrict__ A, const u16* __restrict__ B,
    void* __restrict__ O0, void* __restrict__ O1, void* __restrict__ O2,
    float alpha)
{
    constexpr int K   = (MODE == 2) ? 2048 : 768;
    constexpr int lda = (MODE == 2) ? 2048 : 768;
    constexpr int ldb = (MODE == 2) ? 2048 : 768;

    __shared__ u16 As[128 * 64];   // 16 KB
    __shared__ u16 Bs[128 * 64];   // 16 KB

    const int f = blockIdx.x;
    const int xcd = f & 7;
    const int u = f >> 3;

    int tm, bn, cn, which = 0;
    long aoff = 0, boff = 0;
    if constexpr (MODE == 0) {
        const int c = u >> 4;            // 0..17
        const int rl = u & 15;
        tm = (xcd * 16 + rl) * 128;
        bn = c * 128;
        which = c / 6;
        cn = (c % 6) * 128;
    } else if constexpr (MODE == 1) {
        const int p = u >> 6, t = u & 63, c = t >> 2, rl = t & 3;
        tm = (p * 4 + rl) * 128;
        bn = cn = c * 128;
        aoff = (long)xcd * 2048 * 768;
        boff = aoff;
    } else {
        const int p = u / 12, t = u % 12, c = t >> 1, rl = t & 1;
        tm = (p * 2 + rl) * 128;
        bn = cn = c * 128;
        aoff = (long)xcd * 2048 * 2048;
        boff = (long)xcd * 768 * 2048;
    }

    const u16* Ab = A + aoff;
    const u16* Bb = B + boff;

    const int tid  = threadIdx.x;
    const int lane = tid & 63;
    const int wave = tid >> 6;
    const int wr = wave >> 1;
    const int wc = wave & 1;

    f32x4 acc[4][4] = {};

    // --- staging: thread t -> slots {t+256k}, rows sr+32k, granule g ---
    const int sr = tid >> 3;                 // 0..31
    const int gs = tid & 7;                  // LDS granule slot
    const int g  = gs ^ (sr & 7);            // global column-granule
    const long arow = (long)(tm + sr) * lda + g * 8;
    const long brow = (long)(bn + sr) * ldb + g * 8;

#define STAGE(K0) do { _Pragma("unroll") \
    for (int k = 0; k < 4; ++k) { \
        gld_lds16(Ab + arow + (long)k * 32 * lda + (K0), (void*)(As + (tid + 256 * k) * 8)); \
        gld_lds16(Bb + brow + (long)k * 32 * ldb + (K0), (void*)(Bs + (tid + 256 * k) * 8)); \
    } \
} while (0)

    // --- fragment read bases.  row = base + (lane&15), bases mult of 16 ->
    // row&7 == lane&7.  K-half kk granule q = kk*4 + (lane>>4); slot q^(lane&7).
    const int rr = lane & 15;
    const int lx = lane & 7;
    const int q0 = ((lane >> 4)    ) ^ lx;   // K-half 0 slot
    const int q1 = ((lane >> 4) | 4) ^ lx;   // K-half 1 slot (= q0 ^ 4)
    const u16* a0 = As + (wr * 64 + rr) * 64 + q0 * 8;
    const u16* a1 = As + (wr * 64 + rr) * 64 + q1 * 8;
    const u16* b0 = Bs + (wc * 64 + rr) * 64 + q0 * 8;
    const u16* b1 = Bs + (wc * 64 + rr) * 64 + q1 * 8;

#define HALF(AP, BP) do { \
    short8 a[4], b[4]; \
    _Pragma("unroll") \
    for (int i = 0; i < 4; ++i) a[i] = *(const short8*)((AP) + i * 16 * 64); \
    _Pragma("unroll") \
    for (int j = 0; j < 4; ++j) b[j] = *(const short8*)((BP) + j * 16 * 64); \
    _Pragma("unroll") \
    for (int i = 0; i < 4; ++i) \
    _Pragma("unroll") \
        for (int j = 0; j < 4; ++j) \
            acc[i][j] = __builtin_amdgcn_mfma_f32_16x16x32_bf16( \
                a[i], b[j], acc[i][j], 0, 0, 0); \
} while (0)

#pragma unroll 1
    for (int k0 = 0; k0 < K; k0 += 64) {
        __syncthreads();           // previous tile's readers done (WAR; no DMA pending -> cheap)
        STAGE(k0);
        __syncthreads();           // the ONE drain per 64-K (vmcnt(0) + barrier)
        HALF(a0, b0);              // K-half 0: 16 MFMA
        HALF(a1, b1);              // K-half 1: 16 MFMA
    }

#undef HALF
#undef STAGE

    // Epilogue. C/D layout: col = lane&15, row = (lane>>4)*4 + r
#pragma unroll
    for (int i = 0; i < 4; ++i) {
        const int row0 = tm + wr * 64 + i * 16 + ((lane >> 4) << 2);
#pragma unroll
        for (int j = 0; j < 4; ++j) {
            const int col = cn + wc * 64 + j * 16 + (lane & 15);
#pragma unroll
            for (int r = 0; r < 4; ++r) {
                const int row = row0 + r;
                const float val = acc[i][j][r] * alpha;
                if constexpr (MODE == 0) {
                    if (which == 0)
                        ((u16*)O0)[(long)row * 768 + col] = f2bf(val);
                    else if (which == 1)
                        ((u16*)O1)[(long)row * 768 + col] = f2bf(val);
                    else  // V^T: [b, col, s]
                        ((u16*)O2)[((long)(row >> 11) * 768 + col) * 2048 + (row & 2047)] = f2bf(val);
                } else if constexpr (MODE == 1) {
                    ((u16*)O0)[(long)xcd * 2048 * 2048 + (long)row * 2048 + col] = f2bf(val);
                } else {
                    ((float*)O0)[(long)xcd * 2048 * 768 + (long)row * 768 + col] = val;
                }
            }
        }
    }
}

// ---------------------------------------------------------------------------
__global__ __launch_bounds__(256) void cvt_x_kernel(
    const float4* __restrict__ x, ushort4v* __restrict__ out, int n4)
{
    int i = blockIdx.x * 256 + threadIdx.x;
    if (i < n4) {
        float4 f = x[i];
        ushort4v o;
        o.x = f2bf(f.x); o.y = f2bf(f.y); o.z = f2bf(f.z); o.w = f2bf(f.w);
        out[i] = o;
    }
}

// w[3][768][768] (m,d,o)  ->  wt[3][768][768] (m,o,d), bf16
__global__ __launch_bounds__(256) void cvt_w_kernel(
    const float* __restrict__ w, u16* __restrict__ wt)
{
    int i = blockIdx.x * 256 + threadIdx.x;   // total 3*768*768
    int d = i % 768;
    int o = (i / 768) % 768;
    int m = i / (768 * 768);
    wt[i] = f2bf(w[((long)m * 768 + d) * 768 + o]);
}

// one block per row, 2048 bf16 logits in-place -> softmax probs (bf16)
__global__ __launch_bounds__(256) void softmax_kernel(u16* __restrict__ S)
{
    const long row = blockIdx.x;
    u16* p = S + row * 2048;
    const int t = threadIdx.x;
    const int lane = t & 63;
    const int wave = t >> 6;
    __shared__ float red[8];

    ushort8 raw = *(const ushort8*)(p + t * 8);
    float v[8];
    float m = -1e30f;
#pragma unroll
    for (int i = 0; i < 8; ++i) { v[i] = bf2f(raw[i]); m = fmaxf(m, v[i]); }
#pragma unroll
    for (int off = 1; off < 64; off <<= 1) m = fmaxf(m, __shfl_xor(m, off, 64));
    if (lane == 0) red[wave] = m;
    __syncthreads();
    m = fmaxf(fmaxf(red[0], red[1]), fmaxf(red[2], red[3]));

    float s = 0.f;
#pragma unroll
    for (int i = 0; i < 8; ++i) { v[i] = __expf(v[i] - m); s += v[i]; }
#pragma unroll
    for (int off = 1; off < 64; off <<= 1) s += __shfl_xor(s, off, 64);
    if (lane == 0) red[4 + wave] = s;
    __syncthreads();
    s = (red[4] + red[5]) + (red[6] + red[7]);

    const float inv = 1.0f / s;
    ushort8 out;
#pragma unroll
    for (int i = 0; i < 8; ++i) out[i] = f2bf(v[i] * inv);
    *(ushort8*)(p + t * 8) = out;
}

// ---------------------------------------------------------------------------
extern "C" void kernel_launch(void* const* d_in, const int* in_sizes, int n_in,
                              void* d_out, int out_size, void* d_ws, size_t ws_size,
                              hipStream_t stream)
{
    const float* x  = (const float*)d_in[0];   // [8,2048,768]
    const float* wk = (const float*)d_in[1];   // [3,768,768]
    float* out = (float*)d_out;                // [8,2048,768]

    char* ws = (char*)d_ws;
    u16* xbf = (u16*)(ws);                       // 16384x768        25.2 MB
    u16* wt  = (u16*)(ws + 25165824);            // 3x768x768 (W^T)   3.5 MB
    u16* qbf = (u16*)(ws + 28704768);            // 16384x768        25.2 MB
    u16* kbf = (u16*)(ws + 53870592);            // 16384x768        25.2 MB
    u16* vt  = (u16*)(ws + 79036416);            // 8x768x2048       25.2 MB
    u16* S   = (u16*)(ws + 104202240);           // 8x2048x2048      67.1 MB

    // 1. conversions
    cvt_x_kernel<<<dim3(12288), dim3(256), 0, stream>>>(
        (const float4*)x, (ushort4v*)xbf, 3145728);
    cvt_w_kernel<<<dim3(6912), dim3(256), 0, stream>>>(wk, wt);

    // 2. fused QKV projections (one dispatch, 18 col-tiles share x row-tiles)
    gemm_bt<0><<<dim3(2304), dim3(256), 0, stream>>>(
        xbf, wt, qbf, kbf, vt, 1.0f);

    // 3. logits: S_b = 0.125 * Q_b K_b^T   (batch <-> XCD)
    gemm_bt<1><<<dim3(2048), dim3(256), 0, stream>>>(
        qbf, kbf, S, nullptr, nullptr, 0.125f);

    // 4. softmax rows (in place, bf16)
    softmax_kernel<<<dim3(16384), dim3(256), 0, stream>>>(S);

    // 5. out_b = A_b V_b
    gemm_bt<2><<<dim3(768), dim3(256), 0, stream>>>(
        S, vt, out, nullptr, nullptr, 1.0f);
}